// Round 6
// baseline (246.679 us; speedup 1.0000x reference)
//
#include <hip/hip_runtime.h>
#include <hip/hip_bf16.h>

// Problem constants
#define B_   32
#define N_   2048
#define E_   768
#define OUT_ 384
#define HID_ 16
constexpr int ROWS   = B_ * N_;      // 65536
constexpr int TILE_M = 16;           // rows per block (= per wave)
constexpr int NT     = OUT_ / 16;    // 24 N-tiles of local GEMM
constexpr int KT_L   = 6;            // 6 K-steps (local, K=192)
constexpr int KT_G   = 24;           // 24 K-steps (gate, K=768)
constexpr int S_AL   = 194;          // al row stride in shorts (388 B -> bank-spread)

typedef __attribute__((ext_vector_type(8))) short bf16x8;
typedef __attribute__((ext_vector_type(4))) float f32x4;

__device__ __forceinline__ short f2bf(float f) {
  __hip_bfloat16 h = __float2bfloat16(f);          // RNE; fuses to v_cvt_pk_bf16_f32
  return __builtin_bit_cast(short, h);
}
__device__ __forceinline__ unsigned pack2bf(float lo, float hi) {
  return (unsigned)(unsigned short)f2bf(lo) | ((unsigned)(unsigned short)f2bf(hi) << 16);
}
__device__ __forceinline__ float bfbits_lo(unsigned u) {
  union { unsigned u; float f; } v; v.u = u << 16; return v.f;
}
__device__ __forceinline__ float bfbits_hi(unsigned u) {
  union { unsigned u; float f; } v; v.u = u & 0xffff0000u; return v.f;
}

// Abramowitz-Stegun 7.1.26, |err| <= 1.5e-7, branch-free
__device__ __forceinline__ float fast_erf(float x) {
  const float ax = __builtin_fabsf(x);
  const float t  = __builtin_amdgcn_rcpf(__builtin_fmaf(0.3275911f, ax, 1.0f));
  float p = __builtin_fmaf(1.061405429f, t, -1.453152027f);
  p = __builtin_fmaf(p, t, 1.421413741f);
  p = __builtin_fmaf(p, t, -0.284496736f);
  p = __builtin_fmaf(p, t, 0.254829592f);
  const float e = __expf(-ax * ax);
  const float y = __builtin_fmaf(-p * t, e, 1.0f);
  return __builtin_copysignf(y, x);
}
__device__ __forceinline__ float gelu(float v) {
  return 0.5f * v * (1.0f + fast_erf(v * 0.70710678118654752f));
}

// ---------------- pre-pass: build bf16 MFMA B-fragments in workspace ----------------
// wsL: [NT][KT_L][64 lanes][8]  (w_l fragments)   wsG: [KT_G][64][8] (w_g1 fragments)
__global__ void prep_kernel(const float* __restrict__ w_l, const float* __restrict__ w_g1,
                            short* __restrict__ wsL, short* __restrict__ wsG) {
  int t = blockIdx.x * blockDim.x + threadIdx.x;
  int wave = t >> 6, ln = t & 63;
  int kg = ln >> 4, c16 = ln & 15;
  if (wave < NT * KT_L) {
    int n = wave / KT_L, ks = wave % KT_L;
    bf16x8 v;
#pragma unroll
    for (int j = 0; j < 8; ++j) {
      int k = ks * 32 + kg * 8 + j;
      v[j] = f2bf(w_l[k * OUT_ + n * 16 + c16]);
    }
    *reinterpret_cast<bf16x8*>(&wsL[(size_t)(wave * 64 + ln) * 8]) = v;
  } else if (wave < NT * KT_L + KT_G) {
    int ks = wave - NT * KT_L;
    bf16x8 v;
#pragma unroll
    for (int j = 0; j < 8; ++j) {
      int k = ks * 32 + kg * 8 + j;
      v[j] = f2bf(w_g1[k * HID_ + c16]);
    }
    *reinterpret_cast<bf16x8*>(&wsG[(size_t)(ks * 64 + ln) * 8]) = v;
  }
}

// ---------------- main fused kernel: 64 threads = 1 independent wave, 16 rows ----------------
template <bool USE_WS>
__global__ __launch_bounds__(64, 3)
void spectre_kernel(const float* __restrict__ x,
                    const float* __restrict__ w_g1, const float* __restrict__ b_g1,
                    const float* __restrict__ ln_g_w, const float* __restrict__ ln_g_b,
                    const float* __restrict__ w_g2, const float* __restrict__ b_g2,
                    const float* __restrict__ w_l, const float* __restrict__ b_l,
                    const float* __restrict__ ln_l_w, const float* __restrict__ ln_l_b,
                    const short* __restrict__ wsL, const short* __restrict__ wsG,
                    float* __restrict__ out) {
  __shared__ short al[TILE_M * S_AL];    // 6208 B: local A (x[..., ::4] bf16), [row][local_k]

  const int ln  = threadIdx.x & 63;
  const int kg  = ln >> 4;         // k-group / D-row group
  const int l15 = ln & 15;         // A-row / D-col
  const int row0 = blockIdx.x * TILE_M;

  const float* xb = x + (size_t)row0 * E_;

  // ---- gate GEMM, full K=768 in this wave, 3-slot prefetch ring ----
  f32x4 accg = {0.f, 0.f, 0.f, 0.f};
  {
    const float* pA = xb + l15 * E_ + kg * 8;
    float4 xu0[3], xu1[3];
    bf16x8 gb[3];
#pragma unroll
    for (int s = 0; s < 3; ++s) {
      xu0[s] = *reinterpret_cast<const float4*>(pA + s * 32);
      xu1[s] = *reinterpret_cast<const float4*>(pA + s * 32 + 4);
      if constexpr (USE_WS) {
        gb[s] = *reinterpret_cast<const bf16x8*>(&wsG[(s * 64 + ln) * 8]);
      } else {
#pragma unroll
        for (int j = 0; j < 8; ++j) gb[s][j] = f2bf(w_g1[(s * 32 + kg * 8 + j) * HID_ + l15]);
      }
    }
#pragma unroll
    for (int i = 0; i < KT_G; ++i) {
      const int s = i % 3;
      const float4 u0 = xu0[s];
      const float4 u1 = xu1[s];
      const bf16x8 b  = gb[s];
      if (i + 3 < KT_G) {
        const int k2 = i + 3;
        xu0[s] = *reinterpret_cast<const float4*>(pA + k2 * 32);
        xu1[s] = *reinterpret_cast<const float4*>(pA + k2 * 32 + 4);
        if constexpr (USE_WS) {
          gb[s] = *reinterpret_cast<const bf16x8*>(&wsG[(k2 * 64 + ln) * 8]);
        } else {
#pragma unroll
          for (int j = 0; j < 8; ++j) gb[s][j] = f2bf(w_g1[(k2 * 32 + kg * 8 + j) * HID_ + l15]);
        }
      }
      // local A fragment piece (x cols that are multiples of 4) -> LDS (same-wave, no barrier)
      short2 lv;
      lv.x = f2bf(u0.x);
      lv.y = f2bf(u1.x);
      *reinterpret_cast<short2*>(&al[l15 * S_AL + 8 * i + 2 * kg]) = lv;
      const bf16x8 a = { lv.x, f2bf(u0.y), f2bf(u0.z), f2bf(u0.w),
                         lv.y, f2bf(u1.y), f2bf(u1.z), f2bf(u1.w) };
      accg = __builtin_amdgcn_mfma_f32_16x16x32_bf16(a, b, accg, 0, 0, 0);
    }
  }

  // ---- local A fragments from LDS (compiler inserts lgkmcnt; same wave) ----
  bf16x8 aL[KT_L];
#pragma unroll
  for (int ks = 0; ks < KT_L; ++ks)
    aL[ks] = *reinterpret_cast<const bf16x8*>(&al[l15 * S_AL + ks * 32 + kg * 8]);

  // ---- preload local pair-0 B frags + first bias (in flight during gate finalize) ----
  bf16x8 cur[KT_L], nxt[KT_L];
#pragma unroll
  for (int ks = 0; ks < KT_L; ++ks) {
    if constexpr (USE_WS) {
      cur[ks] = *reinterpret_cast<const bf16x8*>(&wsL[((0 * KT_L + ks) * 64 + ln) * 8]);
    } else {
#pragma unroll
      for (int jj = 0; jj < 8; ++jj)
        cur[ks][jj] = f2bf(w_l[(ks * 32 + kg * 8 + jj) * OUT_ + 0 * 16 + l15]);
    }
  }
  float blc = b_l[l15];

  // ---- gate finalize: LN over 16 (within l15 group), GeLU, dot w_g2 ----
  const float bg  = b_g1[l15];
  const float lgw = ln_g_w[l15];
  const float lgb = ln_g_b[l15];
  const float wg2 = w_g2[l15];
  const float bg2 = b_g2[0];
  float gf[4];
#pragma unroll
  for (int r = 0; r < 4; ++r) {
    const float y = accg[r] + bg;
    float s = y, q = y * y;
#pragma unroll
    for (int m = 1; m < 16; m <<= 1) {
      s += __shfl_xor(s, m);
      q += __shfl_xor(q, m);
    }
    const float mean = s * (1.f / 16.f);
    const float var  = q * (1.f / 16.f) - mean * mean;
    const float rstd = rsqrtf(var + 1e-5f);
    const float vn = (y - mean) * rstd * lgw + lgb;
    float ps = gelu(vn) * wg2;
#pragma unroll
    for (int m = 1; m < 16; m <<= 1) ps += __shfl_xor(ps, m);
    gf[r] = ps + bg2;
  }

  // ---- local GEMM: n-outer, single live acc, hand ping-pong; pre-LN packed to bf16 regs ----
  float s1[4] = {0.f, 0.f, 0.f, 0.f}, s2[4] = {0.f, 0.f, 0.f, 0.f};
  unsigned pk[NT][2];
#pragma unroll
  for (int n = 0; n < NT; ++n) {
    const float bln = (n + 1 < NT) ? b_l[(n + 1) * 16 + l15] : 0.f;
    if (n + 1 < NT) {
#pragma unroll
      for (int ks = 0; ks < KT_L; ++ks) {
        if constexpr (USE_WS) {
          nxt[ks] = *reinterpret_cast<const bf16x8*>(&wsL[(((n + 1) * KT_L + ks) * 64 + ln) * 8]);
        } else {
#pragma unroll
          for (int jj = 0; jj < 8; ++jj)
            nxt[ks][jj] = f2bf(w_l[(ks * 32 + kg * 8 + jj) * OUT_ + (n + 1) * 16 + l15]);
        }
      }
    }
    f32x4 acc = {0.f, 0.f, 0.f, 0.f};
#pragma unroll
    for (int ks = 0; ks < KT_L; ++ks)
      acc = __builtin_amdgcn_mfma_f32_16x16x32_bf16(aL[ks], cur[ks], acc, 0, 0, 0);
    const float v0 = acc[0] + blc, v1 = acc[1] + blc, v2 = acc[2] + blc, v3 = acc[3] + blc;
    s1[0] += v0; s2[0] += v0 * v0;
    s1[1] += v1; s2[1] += v1 * v1;
    s1[2] += v2; s2[2] += v2 * v2;
    s1[3] += v3; s2[3] += v3 * v3;
    pk[n][0] = pack2bf(v0, v1);
    pk[n][1] = pack2bf(v2, v3);
#pragma unroll
    for (int ks = 0; ks < KT_L; ++ks) cur[ks] = nxt[ks];
    blc = bln;
  }

  // ---- LN-384 stats (reduce over the 16 l15 lanes; interleaved chains) ----
#pragma unroll
  for (int m = 1; m < 16; m <<= 1) {
#pragma unroll
    for (int r = 0; r < 4; ++r) {
      s1[r] += __shfl_xor(s1[r], m);
      s2[r] += __shfl_xor(s2[r], m);
    }
  }
  float meanr[4], rstdr[4];
#pragma unroll
  for (int r = 0; r < 4; ++r) {
    meanr[r] = s1[r] * (1.f / 384.f);
    const float var = s2[r] * (1.f / 384.f) - meanr[r] * meanr[r];
    rstdr[r] = rsqrtf(var + 1e-5f);
  }

  // ---- epilogue: LN, GeLU, + pooled (global re-read, L2-warm) + gate; store ----
#pragma unroll
  for (int n = 0; n < NT; ++n) {
    const int col = n * 16 + l15;
    const float lw = ln_l_w[col];
    const float lb = ln_l_b[col];
    const float vv0 = bfbits_lo(pk[n][0]);
    const float vv1 = bfbits_hi(pk[n][0]);
    const float vv2 = bfbits_lo(pk[n][1]);
    const float vv3 = bfbits_hi(pk[n][1]);
#pragma unroll
    for (int r = 0; r < 4; ++r) {
      const int row = kg * 4 + r;
      const float vr = (r == 0) ? vv0 : (r == 1) ? vv1 : (r == 2) ? vv2 : vv3;
      const float2 px = *reinterpret_cast<const float2*>(xb + (size_t)row * E_ + 2 * col);
      const float pooled = 0.5f * (px.x + px.y);
      const float vn = (vr - meanr[r]) * rstdr[r] * lw + lb;
      out[(size_t)(row0 + row) * OUT_ + col] = gelu(vn) + gf[r] + pooled;
    }
  }
}

// ---------------- launch ----------------
extern "C" void kernel_launch(void* const* d_in, const int* in_sizes, int n_in,
                              void* d_out, int out_size, void* d_ws, size_t ws_size,
                              hipStream_t stream) {
  (void)in_sizes; (void)n_in; (void)out_size;
  const float* x      = (const float*)d_in[0];
  const float* w_g1   = (const float*)d_in[1];
  const float* b_g1   = (const float*)d_in[2];
  const float* ln_g_w = (const float*)d_in[3];
  const float* ln_g_b = (const float*)d_in[4];
  const float* w_g2   = (const float*)d_in[5];
  const float* b_g2   = (const float*)d_in[6];
  const float* w_l    = (const float*)d_in[7];
  const float* b_l    = (const float*)d_in[8];
  const float* ln_l_w = (const float*)d_in[9];
  const float* ln_l_b = (const float*)d_in[10];
  float* out = (float*)d_out;

  const size_t needL = (size_t)NT * KT_L * 64 * 8;   // shorts
  const size_t needG = (size_t)KT_G * 64 * 8;        // shorts
  const bool use_ws = ws_size >= (needL + needG) * sizeof(short);

  short* wsL = (short*)d_ws;
  short* wsG = wsL + needL;

  const int grid = ROWS / TILE_M;   // 4096
  if (use_ws) {
    prep_kernel<<<(NT * KT_L + KT_G) * 64 / 256, 256, 0, stream>>>(w_l, w_g1, wsL, wsG);
    spectre_kernel<true><<<grid, 64, 0, stream>>>(x, w_g1, b_g1, ln_g_w, ln_g_b, w_g2, b_g2,
                                                  w_l, b_l, ln_l_w, ln_l_b, wsL, wsG, out);
  } else {
    spectre_kernel<false><<<grid, 64, 0, stream>>>(x, w_g1, b_g1, ln_g_w, ln_g_b, w_g2, b_g2,
                                                   w_l, b_l, ln_l_w, ln_l_b, nullptr, nullptr, out);
  }
}

// Round 7
// 134.512 us; speedup vs baseline: 1.8339x; 1.8339x over previous
//
#include <hip/hip_runtime.h>
#include <hip/hip_bf16.h>

// Problem constants
#define B_   32
#define N_   2048
#define E_   768
#define OUT_ 384
#define HID_ 16
constexpr int ROWS   = B_ * N_;      // 65536
constexpr int TILE_M = 16;           // rows per block (= per wave)
constexpr int NT     = OUT_ / 16;    // 24 N-tiles of local GEMM
constexpr int KT_L   = 6;            // 6 K-steps (local, K=192)
constexpr int KT_G   = 24;           // 24 K-steps (gate, K=768)
constexpr int S_AL   = 194;          // al row stride in shorts (388 B -> bank-spread)

typedef __attribute__((ext_vector_type(8))) short bf16x8;
typedef __attribute__((ext_vector_type(4))) float f32x4;

__device__ __forceinline__ short f2bf(float f) {
  __hip_bfloat16 h = __float2bfloat16(f);          // RNE; fuses to v_cvt_pk_bf16_f32
  return __builtin_bit_cast(short, h);
}

// Abramowitz-Stegun 7.1.26, |err| <= 1.5e-7, branch-free
__device__ __forceinline__ float fast_erf(float x) {
  const float ax = __builtin_fabsf(x);
  const float t  = __builtin_amdgcn_rcpf(__builtin_fmaf(0.3275911f, ax, 1.0f));
  float p = __builtin_fmaf(1.061405429f, t, -1.453152027f);
  p = __builtin_fmaf(p, t, 1.421413741f);
  p = __builtin_fmaf(p, t, -0.284496736f);
  p = __builtin_fmaf(p, t, 0.254829592f);
  const float e = __expf(-ax * ax);
  const float y = __builtin_fmaf(-p * t, e, 1.0f);
  return __builtin_copysignf(y, x);
}
__device__ __forceinline__ float gelu(float v) {
  return 0.5f * v * (1.0f + fast_erf(v * 0.70710678118654752f));
}

// ---------------- pre-pass: build bf16 MFMA B-fragments in workspace ----------------
// wsL: [NT][KT_L][64 lanes][8]  (w_l fragments)   wsG: [KT_G][64][8] (w_g1 fragments)
__global__ void prep_kernel(const float* __restrict__ w_l, const float* __restrict__ w_g1,
                            short* __restrict__ wsL, short* __restrict__ wsG) {
  int t = blockIdx.x * blockDim.x + threadIdx.x;
  int wave = t >> 6, ln = t & 63;
  int kg = ln >> 4, c16 = ln & 15;
  if (wave < NT * KT_L) {
    int n = wave / KT_L, ks = wave % KT_L;
    bf16x8 v;
#pragma unroll
    for (int j = 0; j < 8; ++j) {
      int k = ks * 32 + kg * 8 + j;
      v[j] = f2bf(w_l[k * OUT_ + n * 16 + c16]);
    }
    *reinterpret_cast<bf16x8*>(&wsL[(size_t)(wave * 64 + ln) * 8]) = v;
  } else if (wave < NT * KT_L + KT_G) {
    int ks = wave - NT * KT_L;
    bf16x8 v;
#pragma unroll
    for (int j = 0; j < 8; ++j) {
      int k = ks * 32 + kg * 8 + j;
      v[j] = f2bf(w_g1[k * HID_ + c16]);
    }
    *reinterpret_cast<bf16x8*>(&wsG[(size_t)(ks * 64 + ln) * 8]) = v;
  }
}

// ---------------- main fused kernel: 64 threads = 1 independent wave, 16 rows ----------------
// Two-pass local GEMM: pass1 -> LN stats only; pass2 recomputes + epilogue (no pre-LN stash).
template <bool USE_WS>
__global__ __launch_bounds__(64, 4)
void spectre_kernel(const float* __restrict__ x,
                    const float* __restrict__ w_g1, const float* __restrict__ b_g1,
                    const float* __restrict__ ln_g_w, const float* __restrict__ ln_g_b,
                    const float* __restrict__ w_g2, const float* __restrict__ b_g2,
                    const float* __restrict__ w_l, const float* __restrict__ b_l,
                    const float* __restrict__ ln_l_w, const float* __restrict__ ln_l_b,
                    const short* __restrict__ wsL, const short* __restrict__ wsG,
                    float* __restrict__ out) {
  __shared__ short al[TILE_M * S_AL];    // 6208 B: local A (x[..., ::4] bf16), [row][local_k]

  const int ln  = threadIdx.x & 63;
  const int kg  = ln >> 4;         // k-group / D-row group
  const int l15 = ln & 15;         // A-row / D-col
  const int row0 = blockIdx.x * TILE_M;

  const float* xb = x + (size_t)row0 * E_;

  // ---- gate GEMM, full K=768 in this wave, 3-slot prefetch ring ----
  f32x4 accg = {0.f, 0.f, 0.f, 0.f};
  {
    const float* pA = xb + l15 * E_ + kg * 8;
    float4 xu0[3], xu1[3];
    bf16x8 gb[3];
#pragma unroll
    for (int s = 0; s < 3; ++s) {
      xu0[s] = *reinterpret_cast<const float4*>(pA + s * 32);
      xu1[s] = *reinterpret_cast<const float4*>(pA + s * 32 + 4);
      if constexpr (USE_WS) {
        gb[s] = *reinterpret_cast<const bf16x8*>(&wsG[(s * 64 + ln) * 8]);
      } else {
#pragma unroll
        for (int j = 0; j < 8; ++j) gb[s][j] = f2bf(w_g1[(s * 32 + kg * 8 + j) * HID_ + l15]);
      }
    }
#pragma unroll
    for (int i = 0; i < KT_G; ++i) {
      const int s = i % 3;
      const float4 u0 = xu0[s];
      const float4 u1 = xu1[s];
      const bf16x8 b  = gb[s];
      if (i + 3 < KT_G) {
        const int k2 = i + 3;
        xu0[s] = *reinterpret_cast<const float4*>(pA + k2 * 32);
        xu1[s] = *reinterpret_cast<const float4*>(pA + k2 * 32 + 4);
        if constexpr (USE_WS) {
          gb[s] = *reinterpret_cast<const bf16x8*>(&wsG[(k2 * 64 + ln) * 8]);
        } else {
#pragma unroll
          for (int j = 0; j < 8; ++j) gb[s][j] = f2bf(w_g1[(k2 * 32 + kg * 8 + j) * HID_ + l15]);
        }
      }
      // local A fragment piece (x cols that are multiples of 4) -> LDS (same-wave, no barrier)
      short2 lv;
      lv.x = f2bf(u0.x);
      lv.y = f2bf(u1.x);
      *reinterpret_cast<short2*>(&al[l15 * S_AL + 8 * i + 2 * kg]) = lv;
      const bf16x8 a = { lv.x, f2bf(u0.y), f2bf(u0.z), f2bf(u0.w),
                         lv.y, f2bf(u1.y), f2bf(u1.z), f2bf(u1.w) };
      accg = __builtin_amdgcn_mfma_f32_16x16x32_bf16(a, b, accg, 0, 0, 0);
    }
  }

  // ---- gate finalize: LN over 16 (within l15 group), GeLU, dot w_g2 ----
  const float bg  = b_g1[l15];
  const float lgw = ln_g_w[l15];
  const float lgb = ln_g_b[l15];
  const float wg2 = w_g2[l15];
  const float bg2 = b_g2[0];
  float gf[4];
#pragma unroll
  for (int r = 0; r < 4; ++r) {
    const float y = accg[r] + bg;
    float s = y, q = y * y;
#pragma unroll
    for (int m = 1; m < 16; m <<= 1) {
      s += __shfl_xor(s, m);
      q += __shfl_xor(q, m);
    }
    const float mean = s * (1.f / 16.f);
    const float var  = q * (1.f / 16.f) - mean * mean;
    const float rstd = rsqrtf(var + 1e-5f);
    const float vn = (y - mean) * rstd * lgw + lgb;
    float ps = gelu(vn) * wg2;
#pragma unroll
    for (int m = 1; m < 16; m <<= 1) ps += __shfl_xor(ps, m);
    gf[r] = ps + bg2;
  }

  // ---- local A fragments from LDS (same wave; compiler inserts lgkmcnt) ----
  bf16x8 aL[KT_L];
#pragma unroll
  for (int ks = 0; ks < KT_L; ++ks)
    aL[ks] = *reinterpret_cast<const bf16x8*>(&al[l15 * S_AL + ks * 32 + kg * 8]);

  const short* wp = USE_WS ? (wsL + ln * 8) : nullptr;

  // ================= pass 1: LN-384 stats via MFMA (values not kept) =================
  float s1[4] = {0.f, 0.f, 0.f, 0.f}, s2[4] = {0.f, 0.f, 0.f, 0.f};
  {
    bf16x8 fa[KT_L], fb[KT_L];
    // preload n=0
#pragma unroll
    for (int ks = 0; ks < KT_L; ++ks) {
      if constexpr (USE_WS) {
        fa[ks] = *reinterpret_cast<const bf16x8*>(wp + (0 * KT_L + ks) * 512);
      } else {
#pragma unroll
        for (int jj = 0; jj < 8; ++jj)
          fa[ks][jj] = f2bf(w_l[(ks * 32 + kg * 8 + jj) * OUT_ + 0 * 16 + l15]);
      }
    }
#pragma unroll 1
    for (int p = 0; p < NT / 2; ++p) {
      const int n0 = 2 * p, n1 = 2 * p + 1;
      // prefetch n1 into fb
#pragma unroll
      for (int ks = 0; ks < KT_L; ++ks) {
        if constexpr (USE_WS) {
          fb[ks] = *reinterpret_cast<const bf16x8*>(wp + (n1 * KT_L + ks) * 512);
        } else {
#pragma unroll
          for (int jj = 0; jj < 8; ++jj)
            fb[ks][jj] = f2bf(w_l[(ks * 32 + kg * 8 + jj) * OUT_ + n1 * 16 + l15]);
        }
      }
      const float bl0 = b_l[n0 * 16 + l15];
      f32x4 acc = {0.f, 0.f, 0.f, 0.f};
#pragma unroll
      for (int ks = 0; ks < KT_L; ++ks)
        acc = __builtin_amdgcn_mfma_f32_16x16x32_bf16(aL[ks], fa[ks], acc, 0, 0, 0);
#pragma unroll
      for (int r = 0; r < 4; ++r) {
        const float v = acc[r] + bl0;
        s1[r] += v; s2[r] += v * v;
      }
      // prefetch n0+2 into fa
      if (p + 1 < NT / 2) {
        const int n2 = n0 + 2;
#pragma unroll
        for (int ks = 0; ks < KT_L; ++ks) {
          if constexpr (USE_WS) {
            fa[ks] = *reinterpret_cast<const bf16x8*>(wp + (n2 * KT_L + ks) * 512);
          } else {
#pragma unroll
            for (int jj = 0; jj < 8; ++jj)
              fa[ks][jj] = f2bf(w_l[(ks * 32 + kg * 8 + jj) * OUT_ + n2 * 16 + l15]);
          }
        }
      }
      const float bl1 = b_l[n1 * 16 + l15];
      f32x4 acd = {0.f, 0.f, 0.f, 0.f};
#pragma unroll
      for (int ks = 0; ks < KT_L; ++ks)
        acd = __builtin_amdgcn_mfma_f32_16x16x32_bf16(aL[ks], fb[ks], acd, 0, 0, 0);
#pragma unroll
      for (int r = 0; r < 4; ++r) {
        const float v = acd[r] + bl1;
        s1[r] += v; s2[r] += v * v;
      }
    }
  }

  // ---- LN-384 stats (reduce over the 16 l15 lanes; interleaved chains) ----
#pragma unroll
  for (int m = 1; m < 16; m <<= 1) {
#pragma unroll
    for (int r = 0; r < 4; ++r) {
      s1[r] += __shfl_xor(s1[r], m);
      s2[r] += __shfl_xor(s2[r], m);
    }
  }
  float meanr[4], rstdr[4];
#pragma unroll
  for (int r = 0; r < 4; ++r) {
    meanr[r] = s1[r] * (1.f / 384.f);
    const float var = s2[r] * (1.f / 384.f) - meanr[r] * meanr[r];
    rstdr[r] = rsqrtf(var + 1e-5f);
  }

  // ================= pass 2: recompute + LN + GeLU + pooled + gate + store =================
  {
    bf16x8 fa[KT_L], fb[KT_L];
#pragma unroll
    for (int ks = 0; ks < KT_L; ++ks) {
      if constexpr (USE_WS) {
        fa[ks] = *reinterpret_cast<const bf16x8*>(wp + (0 * KT_L + ks) * 512);
      } else {
#pragma unroll
        for (int jj = 0; jj < 8; ++jj)
          fa[ks][jj] = f2bf(w_l[(ks * 32 + kg * 8 + jj) * OUT_ + 0 * 16 + l15]);
      }
    }
#pragma unroll 1
    for (int p = 0; p < NT / 2; ++p) {
      const int n0 = 2 * p, n1 = 2 * p + 1;
#pragma unroll
      for (int ks = 0; ks < KT_L; ++ks) {
        if constexpr (USE_WS) {
          fb[ks] = *reinterpret_cast<const bf16x8*>(wp + (n1 * KT_L + ks) * 512);
        } else {
#pragma unroll
          for (int jj = 0; jj < 8; ++jj)
            fb[ks][jj] = f2bf(w_l[(ks * 32 + kg * 8 + jj) * OUT_ + n1 * 16 + l15]);
        }
      }
#pragma unroll
      for (int half = 0; half < 2; ++half) {
        const int n = (half == 0) ? n0 : n1;
        const int col = n * 16 + l15;
        const float bln = b_l[col];
        const float lw  = ln_l_w[col];
        const float lb  = ln_l_b[col];
        f32x4 acc = {0.f, 0.f, 0.f, 0.f};
        if (half == 0) {
#pragma unroll
          for (int ks = 0; ks < KT_L; ++ks)
            acc = __builtin_amdgcn_mfma_f32_16x16x32_bf16(aL[ks], fa[ks], acc, 0, 0, 0);
          // prefetch n0+2 into fa while fb's MFMAs run next
          if (p + 1 < NT / 2) {
            const int n2 = n0 + 2;
#pragma unroll
            for (int ks = 0; ks < KT_L; ++ks) {
              if constexpr (USE_WS) {
                fa[ks] = *reinterpret_cast<const bf16x8*>(wp + (n2 * KT_L + ks) * 512);
              } else {
#pragma unroll
                for (int jj = 0; jj < 8; ++jj)
                  fa[ks][jj] = f2bf(w_l[(ks * 32 + kg * 8 + jj) * OUT_ + n2 * 16 + l15]);
              }
            }
          }
        } else {
#pragma unroll
          for (int ks = 0; ks < KT_L; ++ks)
            acc = __builtin_amdgcn_mfma_f32_16x16x32_bf16(aL[ks], fb[ks], acc, 0, 0, 0);
        }
#pragma unroll
        for (int r = 0; r < 4; ++r) {
          const int row = kg * 4 + r;
          const float2 px = *reinterpret_cast<const float2*>(xb + (size_t)row * E_ + 2 * col);
          const float pooled = 0.5f * (px.x + px.y);
          const float v  = acc[r] + bln;
          const float vn = (v - meanr[r]) * rstdr[r] * lw + lb;
          out[(size_t)(row0 + row) * OUT_ + col] = gelu(vn) + gf[r] + pooled;
        }
      }
    }
  }
}

// ---------------- launch ----------------
extern "C" void kernel_launch(void* const* d_in, const int* in_sizes, int n_in,
                              void* d_out, int out_size, void* d_ws, size_t ws_size,
                              hipStream_t stream) {
  (void)in_sizes; (void)n_in; (void)out_size;
  const float* x      = (const float*)d_in[0];
  const float* w_g1   = (const float*)d_in[1];
  const float* b_g1   = (const float*)d_in[2];
  const float* ln_g_w = (const float*)d_in[3];
  const float* ln_g_b = (const float*)d_in[4];
  const float* w_g2   = (const float*)d_in[5];
  const float* b_g2   = (const float*)d_in[6];
  const float* w_l    = (const float*)d_in[7];
  const float* b_l    = (const float*)d_in[8];
  const float* ln_l_w = (const float*)d_in[9];
  const float* ln_l_b = (const float*)d_in[10];
  float* out = (float*)d_out;

  const size_t needL = (size_t)NT * KT_L * 64 * 8;   // shorts
  const size_t needG = (size_t)KT_G * 64 * 8;        // shorts
  const bool use_ws = ws_size >= (needL + needG) * sizeof(short);

  short* wsL = (short*)d_ws;
  short* wsG = wsL + needL;

  const int grid = ROWS / TILE_M;   // 4096
  if (use_ws) {
    prep_kernel<<<(NT * KT_L + KT_G) * 64 / 256, 256, 0, stream>>>(w_l, w_g1, wsL, wsG);
    spectre_kernel<true><<<grid, 64, 0, stream>>>(x, w_g1, b_g1, ln_g_w, ln_g_b, w_g2, b_g2,
                                                  w_l, b_l, ln_l_w, ln_l_b, wsL, wsG, out);
  } else {
    spectre_kernel<false><<<grid, 64, 0, stream>>>(x, w_g1, b_g1, ln_g_w, ln_g_b, w_g2, b_g2,
                                                   w_l, b_l, ln_l_w, ln_l_b, nullptr, nullptr, out);
  }
}

// Round 8
// 101.305 us; speedup vs baseline: 2.4350x; 1.3278x over previous
//
#include <hip/hip_runtime.h>
#include <hip/hip_bf16.h>

// Problem constants
#define B_   32
#define N_   2048
#define E_   768
#define OUT_ 384
#define HID_ 16
constexpr int ROWS   = B_ * N_;      // 65536
constexpr int TILE_M = 16;           // rows per block
constexpr int NT     = OUT_ / 16;    // 24 N-tiles of local GEMM
constexpr int KT_L   = 6;            // 6 K-steps (local, K=192)
constexpr int KT_G   = 24;           // 24 K-steps (gate, K=768)
constexpr int S_AL   = 194;          // al row stride in shorts
constexpr int S_PL   = 392;          // pooled row stride in shorts

typedef __attribute__((ext_vector_type(8))) short bf16x8;
typedef __attribute__((ext_vector_type(4))) float f32x4;

__device__ __forceinline__ short f2bf(float f) {
  __hip_bfloat16 h = __float2bfloat16(f);          // RNE hardware cvt
  return __builtin_bit_cast(short, h);
}
__device__ __forceinline__ float bf2f(short s) {
  union { unsigned u; float f; } v; v.u = ((unsigned)(unsigned short)s) << 16;
  return v.f;
}

// Abramowitz-Stegun 7.1.26, |err| <= 1.5e-7, branch-free
__device__ __forceinline__ float fast_erf(float x) {
  const float ax = __builtin_fabsf(x);
  const float t  = __builtin_amdgcn_rcpf(__builtin_fmaf(0.3275911f, ax, 1.0f));
  float p = __builtin_fmaf(1.061405429f, t, -1.453152027f);
  p = __builtin_fmaf(p, t, 1.421413741f);
  p = __builtin_fmaf(p, t, -0.284496736f);
  p = __builtin_fmaf(p, t, 0.254829592f);
  const float e = __expf(-ax * ax);
  const float y = __builtin_fmaf(-p * t, e, 1.0f);
  return __builtin_copysignf(y, x);
}
__device__ __forceinline__ float gelu(float v) {
  return 0.5f * v * (1.0f + fast_erf(v * 0.70710678118654752f));
}

// ---------------- pre-pass: build bf16 MFMA B-fragments in workspace ----------------
__global__ void prep_kernel(const float* __restrict__ w_l, const float* __restrict__ w_g1,
                            short* __restrict__ wsL, short* __restrict__ wsG) {
  int t = blockIdx.x * blockDim.x + threadIdx.x;
  int wave = t >> 6, ln = t & 63;
  int kg = ln >> 4, c16 = ln & 15;
  if (wave < NT * KT_L) {
    int n = wave / KT_L, ks = wave % KT_L;
    bf16x8 v;
#pragma unroll
    for (int j = 0; j < 8; ++j) {
      int k = ks * 32 + kg * 8 + j;
      v[j] = f2bf(w_l[k * OUT_ + n * 16 + c16]);
    }
    *reinterpret_cast<bf16x8*>(&wsL[(size_t)(wave * 64 + ln) * 8]) = v;
  } else if (wave < NT * KT_L + KT_G) {
    int ks = wave - NT * KT_L;
    bf16x8 v;
#pragma unroll
    for (int j = 0; j < 8; ++j) {
      int k = ks * 32 + kg * 8 + j;
      v[j] = f2bf(w_g1[k * HID_ + c16]);
    }
    *reinterpret_cast<bf16x8*>(&wsG[(size_t)(ks * 64 + ln) * 8]) = v;
  }
}

// ---------------- main fused kernel: 128 threads = 2 waves own 16 rows ----------------
template <bool USE_WS>
__global__ __launch_bounds__(128, 3)
void spectre_kernel(const float* __restrict__ x,
                    const float* __restrict__ w_g1, const float* __restrict__ b_g1,
                    const float* __restrict__ ln_g_w, const float* __restrict__ ln_g_b,
                    const float* __restrict__ w_g2, const float* __restrict__ b_g2,
                    const float* __restrict__ w_l, const float* __restrict__ b_l,
                    const float* __restrict__ ln_l_w, const float* __restrict__ ln_l_b,
                    const short* __restrict__ wsL, const short* __restrict__ wsG,
                    float* __restrict__ out) {
  __shared__ short al[TILE_M * S_AL];    // 6208 B: local A (x[..., ::4] bf16), [row][local_k]
  __shared__ short pl[TILE_M * S_PL];    // 12544 B: pooled (bf16), [row][out_col]
  __shared__ float red2[2][16][17];      // 2176 B: gate partial sums per wave
  __shared__ float reds[2][16][2];       // 256 B : local LN partials per wave

  const int tid = threadIdx.x;
  const int wv  = tid >> 6;        // wave 0..1
  const int ln  = tid & 63;        // lane
  const int kg  = ln >> 4;         // k-group / D-row group
  const int l15 = ln & 15;         // A-row / D-col
  const int row0 = blockIdx.x * TILE_M;

  const float* xb = x + (size_t)row0 * E_;

  // ---- gate GEMM partial (wave wv: K-steps [12wv,12wv+12)) ----
  // Burst-issue ALL x loads (24 dwordx4) + all 12 weight frags up front: deep MLP.
  f32x4 accg = {0.f, 0.f, 0.f, 0.f};
  {
    const float* pA = xb + l15 * E_ + kg * 8;
    float4 xa0[6], xa1[6], xc0[6], xc1[6];
    bf16x8 ga[6], gc[6];
#pragma unroll
    for (int i = 0; i < 6; ++i) {
      const int ks = wv * 12 + i;
      xa0[i] = *reinterpret_cast<const float4*>(pA + ks * 32);
      xa1[i] = *reinterpret_cast<const float4*>(pA + ks * 32 + 4);
    }
#pragma unroll
    for (int i = 0; i < 6; ++i) {
      const int ks = wv * 12 + 6 + i;
      xc0[i] = *reinterpret_cast<const float4*>(pA + ks * 32);
      xc1[i] = *reinterpret_cast<const float4*>(pA + ks * 32 + 4);
    }
    if constexpr (USE_WS) {
#pragma unroll
      for (int i = 0; i < 6; ++i)
        ga[i] = *reinterpret_cast<const bf16x8*>(&wsG[((wv * 12 + i) * 64 + ln) * 8]);
#pragma unroll
      for (int i = 0; i < 6; ++i)
        gc[i] = *reinterpret_cast<const bf16x8*>(&wsG[((wv * 12 + 6 + i) * 64 + ln) * 8]);
    } else {
#pragma unroll
      for (int i = 0; i < 6; ++i) {
        const int ks = wv * 12 + i;
#pragma unroll
        for (int j = 0; j < 8; ++j) ga[i][j] = f2bf(w_g1[(ks * 32 + kg * 8 + j) * HID_ + l15]);
      }
#pragma unroll
      for (int i = 0; i < 6; ++i) {
        const int ks = wv * 12 + 6 + i;
#pragma unroll
        for (int j = 0; j < 8; ++j) gc[i][j] = f2bf(w_g1[(ks * 32 + kg * 8 + j) * HID_ + l15]);
      }
    }
    // process set A
#pragma unroll
    for (int i = 0; i < 6; ++i) {
      const int ks = wv * 12 + i;
      const float4 u0 = xa0[i];
      const float4 u1 = xa1[i];
      short2 lv;
      lv.x = f2bf(u0.x);
      lv.y = f2bf(u1.x);
      *reinterpret_cast<short2*>(&al[l15 * S_AL + 8 * ks + 2 * kg]) = lv;
      short4 pv;
      pv.x = f2bf(0.5f * (u0.x + u0.y));
      pv.y = f2bf(0.5f * (u0.z + u0.w));
      pv.z = f2bf(0.5f * (u1.x + u1.y));
      pv.w = f2bf(0.5f * (u1.z + u1.w));
      *reinterpret_cast<short4*>(&pl[l15 * S_PL + ks * 16 + kg * 4]) = pv;
      const bf16x8 a = { lv.x, f2bf(u0.y), f2bf(u0.z), f2bf(u0.w),
                         lv.y, f2bf(u1.y), f2bf(u1.z), f2bf(u1.w) };
      accg = __builtin_amdgcn_mfma_f32_16x16x32_bf16(a, ga[i], accg, 0, 0, 0);
    }
    // process set C
#pragma unroll
    for (int i = 0; i < 6; ++i) {
      const int ks = wv * 12 + 6 + i;
      const float4 u0 = xc0[i];
      const float4 u1 = xc1[i];
      short2 lv;
      lv.x = f2bf(u0.x);
      lv.y = f2bf(u1.x);
      *reinterpret_cast<short2*>(&al[l15 * S_AL + 8 * ks + 2 * kg]) = lv;
      short4 pv;
      pv.x = f2bf(0.5f * (u0.x + u0.y));
      pv.y = f2bf(0.5f * (u0.z + u0.w));
      pv.z = f2bf(0.5f * (u1.x + u1.y));
      pv.w = f2bf(0.5f * (u1.z + u1.w));
      *reinterpret_cast<short4*>(&pl[l15 * S_PL + ks * 16 + kg * 4]) = pv;
      const bf16x8 a = { lv.x, f2bf(u0.y), f2bf(u0.z), f2bf(u0.w),
                         lv.y, f2bf(u1.y), f2bf(u1.z), f2bf(u1.w) };
      accg = __builtin_amdgcn_mfma_f32_16x16x32_bf16(a, gc[i], accg, 0, 0, 0);
    }
  }
#pragma unroll
  for (int r = 0; r < 4; ++r) red2[wv][kg * 4 + r][l15] = accg[r];

  // hoist per-lane constants (latency hidden under barrier + local GEMM)
  const float bg  = b_g1[l15];
  const float lgw = ln_g_w[l15];
  const float lgb = ln_g_b[l15];
  const float wg2 = w_g2[l15];
  const float bg2 = b_g2[0];
  float blv[12];
#pragma unroll
  for (int n = 0; n < 12; ++n) blv[n] = b_l[(wv * 12 + n) * 16 + l15];

  __syncthreads();   // al + pl + red2 visible

  // ---- local GEMM: ks-outer, ping-pong prefetch of 6-fragment wsL groups ----
  f32x4 acc[12];
#pragma unroll
  for (int n = 0; n < 12; ++n) acc[n] = (f32x4){0.f, 0.f, 0.f, 0.f};

  bf16x8 bb[2][6];
#pragma unroll
  for (int j = 0; j < 6; ++j) {
    const int ng = wv * 12 + j;
    if constexpr (USE_WS) {
      bb[0][j] = *reinterpret_cast<const bf16x8*>(&wsL[((ng * KT_L + 0) * 64 + ln) * 8]);
    } else {
#pragma unroll
      for (int jj = 0; jj < 8; ++jj)
        bb[0][j][jj] = f2bf(w_l[(0 * 32 + kg * 8 + jj) * OUT_ + ng * 16 + l15]);
    }
  }
  bf16x8 aLc = *reinterpret_cast<const bf16x8*>(&al[l15 * S_AL + kg * 8]);
  bf16x8 aLn;
#pragma unroll
  for (int ks = 0; ks < KT_L; ++ks) {
    // prefetch group (ks, h=1)
#pragma unroll
    for (int j = 0; j < 6; ++j) {
      const int ng = wv * 12 + 6 + j;
      if constexpr (USE_WS) {
        bb[1][j] = *reinterpret_cast<const bf16x8*>(&wsL[((ng * KT_L + ks) * 64 + ln) * 8]);
      } else {
#pragma unroll
        for (int jj = 0; jj < 8; ++jj)
          bb[1][j][jj] = f2bf(w_l[(ks * 32 + kg * 8 + jj) * OUT_ + ng * 16 + l15]);
      }
    }
#pragma unroll
    for (int j = 0; j < 6; ++j)
      acc[j] = __builtin_amdgcn_mfma_f32_16x16x32_bf16(aLc, bb[0][j], acc[j], 0, 0, 0);
    // prefetch group (ks+1, h=0) and next A fragment
    if (ks < KT_L - 1) {
      aLn = *reinterpret_cast<const bf16x8*>(&al[l15 * S_AL + (ks + 1) * 32 + kg * 8]);
#pragma unroll
      for (int j = 0; j < 6; ++j) {
        const int ng = wv * 12 + j;
        if constexpr (USE_WS) {
          bb[0][j] = *reinterpret_cast<const bf16x8*>(&wsL[((ng * KT_L + ks + 1) * 64 + ln) * 8]);
        } else {
#pragma unroll
          for (int jj = 0; jj < 8; ++jj)
            bb[0][j][jj] = f2bf(w_l[((ks + 1) * 32 + kg * 8 + jj) * OUT_ + ng * 16 + l15]);
        }
      }
    }
#pragma unroll
    for (int j = 0; j < 6; ++j)
      acc[6 + j] = __builtin_amdgcn_mfma_f32_16x16x32_bf16(aLc, bb[1][j], acc[6 + j], 0, 0, 0);
    if (ks < KT_L - 1) aLc = aLn;
  }

  // ---- add b_l, per-row LN stats over this wave's 192 cols ----
  float s1[4] = {0.f, 0.f, 0.f, 0.f}, s2[4] = {0.f, 0.f, 0.f, 0.f};
#pragma unroll
  for (int n = 0; n < 12; ++n) {
#pragma unroll
    for (int r = 0; r < 4; ++r) {
      const float v = acc[n][r] + blv[n];
      acc[n][r] = v;
      s1[r] += v;
      s2[r] += v * v;
    }
  }
#pragma unroll
  for (int m = 1; m < 16; m <<= 1) {
#pragma unroll
    for (int r = 0; r < 4; ++r) {
      s1[r] += __shfl_xor(s1[r], m);
      s2[r] += __shfl_xor(s2[r], m);
    }
  }
  if (l15 == 0) {
#pragma unroll
    for (int r = 0; r < 4; ++r) {
      reds[wv][kg * 4 + r][0] = s1[r];
      reds[wv][kg * 4 + r][1] = s2[r];
    }
  }
  __syncthreads();

  // hoist LN-local params (latency hidden under gate finalize)
  float lwv[12], lbv[12];
#pragma unroll
  for (int n = 0; n < 12; ++n) {
    const int col = (wv * 12 + n) * 16 + l15;
    lwv[n] = ln_l_w[col];
    lbv[n] = ln_l_b[col];
  }

  // ---- gate finalize: combine wave partials, LN over 16, GeLU, dot w_g2 ----
  float gf[4];
#pragma unroll
  for (int r = 0; r < 4; ++r) {
    const int row = kg * 4 + r;
    const float y = red2[0][row][l15] + red2[1][row][l15] + bg;
    float s = y, q = y * y;
#pragma unroll
    for (int m = 1; m < 16; m <<= 1) {
      s += __shfl_xor(s, m);
      q += __shfl_xor(q, m);
    }
    const float mean = s * (1.f / 16.f);
    const float var  = q * (1.f / 16.f) - mean * mean;
    const float rstd = rsqrtf(var + 1e-5f);
    const float vn = (y - mean) * rstd * lgw + lgb;
    float ps = gelu(vn) * wg2;
#pragma unroll
    for (int m = 1; m < 16; m <<= 1) ps += __shfl_xor(ps, m);
    gf[r] = ps + bg2;
  }

  // ---- local finalize: LN over 384, GeLU, + pooled (LDS) + gate ----
  float meanr[4], rstdr[4];
#pragma unroll
  for (int r = 0; r < 4; ++r) {
    const int row = kg * 4 + r;
    const float t1 = reds[0][row][0] + reds[1][row][0];
    const float t2 = reds[0][row][1] + reds[1][row][1];
    meanr[r] = t1 * (1.f / 384.f);
    const float var = t2 * (1.f / 384.f) - meanr[r] * meanr[r];
    rstdr[r] = rsqrtf(var + 1e-5f);
  }
#pragma unroll
  for (int n = 0; n < 12; ++n) {
    const int col = (wv * 12 + n) * 16 + l15;
#pragma unroll
    for (int r = 0; r < 4; ++r) {
      const int row = kg * 4 + r;
      const float pooled = bf2f(pl[row * S_PL + col]);
      const float vn = (acc[n][r] - meanr[r]) * rstdr[r] * lwv[n] + lbv[n];
      out[(size_t)(row0 + row) * OUT_ + col] = gelu(vn) + gf[r] + pooled;
    }
  }
}

// ---------------- launch ----------------
extern "C" void kernel_launch(void* const* d_in, const int* in_sizes, int n_in,
                              void* d_out, int out_size, void* d_ws, size_t ws_size,
                              hipStream_t stream) {
  (void)in_sizes; (void)n_in; (void)out_size;
  const float* x      = (const float*)d_in[0];
  const float* w_g1   = (const float*)d_in[1];
  const float* b_g1   = (const float*)d_in[2];
  const float* ln_g_w = (const float*)d_in[3];
  const float* ln_g_b = (const float*)d_in[4];
  const float* w_g2   = (const float*)d_in[5];
  const float* b_g2   = (const float*)d_in[6];
  const float* w_l    = (const float*)d_in[7];
  const float* b_l    = (const float*)d_in[8];
  const float* ln_l_w = (const float*)d_in[9];
  const float* ln_l_b = (const float*)d_in[10];
  float* out = (float*)d_out;

  const size_t needL = (size_t)NT * KT_L * 64 * 8;   // shorts
  const size_t needG = (size_t)KT_G * 64 * 8;        // shorts
  const bool use_ws = ws_size >= (needL + needG) * sizeof(short);

  short* wsL = (short*)d_ws;
  short* wsG = wsL + needL;

  const int grid = ROWS / TILE_M;   // 4096
  if (use_ws) {
    prep_kernel<<<(NT * KT_L + KT_G) * 64 / 256, 256, 0, stream>>>(w_l, w_g1, wsL, wsG);
    spectre_kernel<true><<<grid, 128, 0, stream>>>(x, w_g1, b_g1, ln_g_w, ln_g_b, w_g2, b_g2,
                                                   w_l, b_l, ln_l_w, ln_l_b, wsL, wsG, out);
  } else {
    spectre_kernel<false><<<grid, 128, 0, stream>>>(x, w_g1, b_g1, ln_g_w, ln_g_b, w_g2, b_g2,
                                                    w_l, b_l, ln_l_w, ln_l_b, nullptr, nullptr, out);
  }
}